// Round 15
// baseline (162.987 us; speedup 1.0000x reference)
//
#include <hip/hip_runtime.h>
#include <stdint.h>

typedef __attribute__((ext_vector_type(8))) short s16x8;
typedef __attribute__((ext_vector_type(4))) float f32x4;

__device__ __forceinline__ short f2bf(float f){
  union { float f; uint32_t u; } v; v.f = f;
  uint32_t u = v.u;
  u += 0x7fffu + ((u >> 16) & 1u);
  return (short)(u >> 16);
}

#define MFMA16(a, b, c) __builtin_amdgcn_mfma_f32_16x16x32_bf16((a), (b), (c), 0, 0, 0)

// Fused TemporalEncoder. Round-15 = round-14 (validated barrier-free GRU:
// wave owns 4 seqs, computes all 192 gate dims, 14 barriers total) with the
// spill fixed:
//  * Wih B-frags in REGISTERS (WihB[12], 48 VGPR) instead of LDS -- kills the
//    12 ds_reads/step AND their live temporaries (r14: 136 LDS instr/CU/step
//    ~1400cy + 60MB scratch traffic = the entire 142us wall).
//  * sched_barrier(0) after each G-group cages register liveness to one
//    9-MFMA window (r14's unrolled loop held 4 windows live -> spill).
// Static VGPR ~220 (Whh 96 + Wih 48 + biases 16 + conv 12 + state ~48).
__global__ __launch_bounds__(256, 2) void te_fused(
    const float* __restrict__ x,
    const float* __restrict__ w1, const float* __restrict__ b1,
    const float* __restrict__ w2, const float* __restrict__ b2,
    const float* __restrict__ Wih, const float* __restrict__ Whh,
    const float* __restrict__ bih, const float* __restrict__ bhh,
    float* __restrict__ out)
{
  __shared__ float x_s[16 * 100];      // 6400 B
  __shared__ short c1b[16 * 328];      // 10496 B
  __shared__ short s_b[16 * 640];      // 20480 B [t][seq][40-pad ch]
  __shared__ float hscr[4][4 * 68];    // 4352 B  [wave][seq(4)][68-pad dim] f32

  const int tid  = threadIdx.x;
  const int lane = tid & 63;
  const int wv   = tid >> 6;
  const int l15  = lane & 15;
  const int lg   = lane >> 4;
  const int seq0 = blockIdx.x * 16;

  // ---- stage x ----
  {
    const float4* gx = reinterpret_cast<const float4*>(x + (size_t)seq0 * 100);
    float4* sx = reinterpret_cast<float4*>(x_s);
    for (int i = tid; i < 400; i += 256) sx[i] = gx[i];
  }

  // ---- Whh + Wih B-frags: all tiles in regs (96 + 48 VGPR) ----
  // tile g: rows n = 16g+l15; Whh k = ks*32+lg*8+j; Wih k = lg*8+j.
  // tiles 0-7 (r,z): x -log2e ; tiles 8-11 (n): x 2log2e.
  s16x8 WhhB[12][2], WihB[12];
#pragma unroll
  for (int g = 0; g < 12; ++g) {
    const float gs = (g < 8) ? -1.44269504f : 2.88539008f;
    const int n = 16 * g + l15;
#pragma unroll
    for (int ks = 0; ks < 2; ++ks) {
      const float* p = Whh + n * 64 + ks * 32 + lg * 8;
#pragma unroll
      for (int j = 0; j < 8; ++j) WhhB[g][ks][j] = f2bf(gs * p[j]);
    }
    const float* q = Wih + n * 32 + lg * 8;
#pragma unroll
    for (int j = 0; j < 8; ++j) WihB[g][j] = f2bf(gs * q[j]);
  }

  // ---- per-lane biases for (dim = 16G + l15) ----
  float brL[4], bzL[4], bxnL[4], bhnL[4];
#pragma unroll
  for (int G = 0; G < 4; ++G) {
    const int d = 16 * G + l15;
    brL[G]  = -1.44269504f * (bih[d] + bhh[d]);
    bzL[G]  = -1.44269504f * (bih[64 + d] + bhh[64 + d]);
    bxnL[G] =  2.88539008f * bih[128 + d];
    bhnL[G] =  2.88539008f * bhh[128 + d];
  }

  // ---- conv2 B-frags (r11/r14 verbatim) ----
  s16x8 cW2[2];
  f32x4 b2v4;
  {
    const int ch = 16 * (wv & 1) + l15;
    float bv = b2[ch];
    b2v4 = (f32x4){bv, bv, bv, bv};
#pragma unroll
    for (int ks = 0; ks < 2; ++ks) {
      s16x8 h8;
#pragma unroll
      for (int j = 0; j < 8; ++j) {
        const int k = ks * 32 + lg * 8 + j;
        const int g = k >> 4, ii = k & 15;
        h8[j] = (g < 3) ? f2bf(w2[ch * 48 + ii * 3 + g]) : (short)0;
      }
      cW2[ks] = h8;
    }
  }

  // ---- conv1 (r11/r14 verbatim) ----
  const int sl  = tid >> 4;
  const int chc = tid & 15;
  const float w1v0 = w1[chc * 3 + 0], w1v1 = w1[chc * 3 + 1], w1v2 = w1[chc * 3 + 2];
  const float b1v = b1[chc];

  // ---- pointers ----
  const short* c1Rd = &c1b[0] + l15 * 328 + lg * 8;
  short*       sWr  = &s_b[0] + (lg * 4) * 40 + (wv & 1) * 16 + l15;
  short*       c1Wr = &c1b[0] + sl * 328 + chc;
  const float* xRd  = &x_s[sl * 100];
  const int    ub   = (wv >> 1) * 8;
  const short* sRdW = &s_b[0] + (wv * 4 + (l15 & 3)) * 40 + lg * 8;
  float*       hscrW = &hscr[wv][0];
  const bool lb0 = (lg & 1) != 0;
  const bool lb1 = (lg & 2) != 0;

  __syncthreads();

  float hG[4] = {0.f, 0.f, 0.f, 0.f};
  s16x8 ah0 = (s16x8){0, 0, 0, 0, 0, 0, 0, 0};
  s16x8 ah1 = (s16x8){0, 0, 0, 0, 0, 0, 0, 0};

#define CONV1_PHASE(T0_, CLAMP_) do {                                         \
    float xa, xb;                                                             \
    if (CLAMP_) {                                                             \
      const int xi0 = (T0_) - 4, xi1 = (T0_) - 3;                             \
      xa = (xi0 < 0) ? 0.f : xRd[xi0 < 0 ? 0 : (xi0 > 99 ? 99 : xi0)];        \
      xb = (xi1 < 0) ? 0.f : xRd[xi1 < 0 ? 0 : (xi1 > 99 ? 99 : xi1)];        \
    } else {                                                                  \
      xa = xRd[(T0_) - 4]; xb = xRd[(T0_) - 3];                               \
    }                                                                         \
    _Pragma("unroll")                                                         \
    for (int i = 0; i < 19; ++i) {                                            \
      const int xi = (T0_) - 2 + i;                                           \
      float xc;                                                               \
      if (CLAMP_) {                                                           \
        const int idx = xi < 0 ? 0 : (xi > 99 ? 99 : xi);                     \
        xc = (xi < 0) ? 0.f : xRd[idx];                                       \
      } else {                                                                \
        xc = xRd[xi];                                                         \
      }                                                                       \
      float c = __builtin_fmaf(w1v0, xa,                                      \
                __builtin_fmaf(w1v1, xb,                                      \
                __builtin_fmaf(w1v2, xc, b1v)));                              \
      c = c > 0.f ? c : 0.f;                                                  \
      if (CLAMP_) c = (xi < 0) ? 0.f : c;                                     \
      uint32_t cu;                                                            \
      asm("v_cvt_pk_bf16_f32 %0, %1, %2" : "=v"(cu) : "v"(c), "v"(c));        \
      c1Wr[i * 16] = (short)(cu & 0xffff);                                    \
      xa = xb; xb = xc;                                                       \
    }                                                                         \
  } while (0)

#define CONV2_PHASE() do {                                                    \
    _Pragma("unroll")                                                         \
    for (int i = 0; i < 8; ++i) {                                             \
      const int u = ub + i;                                                   \
      s16x8 a0 = *reinterpret_cast<const s16x8*>(c1Rd + u * 16);              \
      s16x8 a1 = *reinterpret_cast<const s16x8*>(c1Rd + u * 16 + 32);         \
      f32x4 sa = MFMA16(a1, cW2[1], MFMA16(a0, cW2[0], b2v4));                \
      float m0 = sa[0] > 0.f ? sa[0] : 0.f;                                   \
      float m1 = sa[1] > 0.f ? sa[1] : 0.f;                                   \
      float m2 = sa[2] > 0.f ? sa[2] : 0.f;                                   \
      float m3 = sa[3] > 0.f ? sa[3] : 0.f;                                   \
      uint32_t u01, u23;                                                      \
      asm("v_cvt_pk_bf16_f32 %0, %1, %2" : "=v"(u01) : "v"(m0), "v"(m1));     \
      asm("v_cvt_pk_bf16_f32 %0, %1, %2" : "=v"(u23) : "v"(m2), "v"(m3));     \
      sWr[u * 640 +   0] = (short)(u01 & 0xffff);                             \
      sWr[u * 640 +  40] = (short)(u01 >> 16);                                \
      sWr[u * 640 +  80] = (short)(u23 & 0xffff);                             \
      sWr[u * 640 + 120] = (short)(u23 >> 16);                                \
    }                                                                         \
  } while (0)

  // select component lg of an f32x4 (D row = lg*4+reg -> seq = reg&3; picking
  // reg = lg yields this lane's element (seq = (5lg)&3 = lg, dim = 16G+l15))
#define SEL4(Q_) (lb1 ? (lb0 ? (Q_)[3] : (Q_)[2]) : (lb0 ? (Q_)[1] : (Q_)[0]))

#pragma unroll 1
  for (int k = 0; k < 7; ++k) {
    const int t0 = k * 16;
    const int NS = (k < 6) ? 16 : 4;

    if (k == 0 || k == 6) CONV1_PHASE(t0, true);
    else                  CONV1_PHASE(t0, false);
    __syncthreads();
    CONV2_PHASE();
    __syncthreads();

#pragma unroll 1
    for (int tl = 0; tl < NS; ++tl) {
      s16x8 sfrag = *reinterpret_cast<const s16x8*>(sRdW + tl * 640);
      const f32x4 z4 = {0.f, 0.f, 0.f, 0.f};
#pragma unroll
      for (int G = 0; G < 4; ++G) {
        __builtin_amdgcn_s_setprio(1);
        f32x4 Qr = MFMA16(ah1, WhhB[G][1],
                   MFMA16(ah0, WhhB[G][0],
                   MFMA16(sfrag, WihB[G], z4)));
        f32x4 Qz = MFMA16(ah1, WhhB[G + 4][1],
                   MFMA16(ah0, WhhB[G + 4][0],
                   MFMA16(sfrag, WihB[G + 4], z4)));
        f32x4 Qxn = MFMA16(sfrag, WihB[G + 8], z4);
        f32x4 Qhn = MFMA16(ah1, WhhB[G + 8][1],
                    MFMA16(ah0, WhhB[G + 8][0], z4));
        __builtin_amdgcn_s_setprio(0);
        float pr = SEL4(Qr)  + brL[G];
        float pz = SEL4(Qz)  + bzL[G];
        float xn = SEL4(Qxn) + bxnL[G];
        float hn = SEL4(Qhn) + bhnL[G];
        float r = __builtin_amdgcn_rcpf(1.f + __builtin_amdgcn_exp2f(pr));
        float z = __builtin_amdgcn_rcpf(1.f + __builtin_amdgcn_exp2f(pz));
        float arg = __builtin_fmaf(r, hn, xn);
        float tn = __builtin_fmaf(-2.f,
                   __builtin_amdgcn_rcpf(__builtin_amdgcn_exp2f(arg) + 1.f), 1.f);
        float h = __builtin_fmaf(z, hG[G] - tn, tn);
        hG[G] = h;
        hscrW[lg * 68 + 16 * G + l15] = h;   // [seq=lg][dim]
        __builtin_amdgcn_sched_barrier(0);   // cage liveness to one G window
      }
      // rebuild next step's A-frags: row l15 -> seq l15&3, k = lg*8+j (+32)
      const float* hrow = hscrW + (l15 & 3) * 68 + lg * 8;
      f32x4 ha = *reinterpret_cast<const f32x4*>(hrow);
      f32x4 hb = *reinterpret_cast<const f32x4*>(hrow + 4);
      f32x4 hc = *reinterpret_cast<const f32x4*>(hrow + 32);
      f32x4 hd = *reinterpret_cast<const f32x4*>(hrow + 36);
      union { s16x8 v; uint32_t u[4]; } fa, fb;
      asm("v_cvt_pk_bf16_f32 %0, %1, %2" : "=v"(fa.u[0]) : "v"(ha[0]), "v"(ha[1]));
      asm("v_cvt_pk_bf16_f32 %0, %1, %2" : "=v"(fa.u[1]) : "v"(ha[2]), "v"(ha[3]));
      asm("v_cvt_pk_bf16_f32 %0, %1, %2" : "=v"(fa.u[2]) : "v"(hb[0]), "v"(hb[1]));
      asm("v_cvt_pk_bf16_f32 %0, %1, %2" : "=v"(fa.u[3]) : "v"(hb[2]), "v"(hb[3]));
      asm("v_cvt_pk_bf16_f32 %0, %1, %2" : "=v"(fb.u[0]) : "v"(hc[0]), "v"(hc[1]));
      asm("v_cvt_pk_bf16_f32 %0, %1, %2" : "=v"(fb.u[1]) : "v"(hc[2]), "v"(hc[3]));
      asm("v_cvt_pk_bf16_f32 %0, %1, %2" : "=v"(fb.u[2]) : "v"(hd[0]), "v"(hd[1]));
      asm("v_cvt_pk_bf16_f32 %0, %1, %2" : "=v"(fb.u[3]) : "v"(hd[2]), "v"(hd[3]));
      ah0 = fa.v; ah1 = fb.v;
    }
  }

  // ---- output: lane holds h(seq = wv*4+lg, dim = 16G+l15) ----
  {
    float* op = out + (size_t)(seq0 + wv * 4 + lg) * 64 + l15;
#pragma unroll
    for (int G = 0; G < 4; ++G) op[16 * G] = hG[G];
  }
}

extern "C" void kernel_launch(void* const* d_in, const int* in_sizes, int n_in,
                              void* d_out, int out_size, void* d_ws, size_t ws_size,
                              hipStream_t stream)
{
  (void)in_sizes; (void)n_in; (void)d_ws; (void)ws_size; (void)out_size;
  const float* x   = (const float*)d_in[0];
  const float* w1  = (const float*)d_in[1];
  const float* b1  = (const float*)d_in[2];
  const float* w2  = (const float*)d_in[3];
  const float* b2  = (const float*)d_in[4];
  const float* Wih = (const float*)d_in[5];
  const float* Whh = (const float*)d_in[6];
  const float* bih = (const float*)d_in[7];
  const float* bhh = (const float*)d_in[8];
  float* out = (float*)d_out;
  te_fused<<<512, 256, 0, stream>>>(x, w1, b1, w2, b2, Wih, Whh, bih, bhh, out);
}

// Round 16
// 139.842 us; speedup vs baseline: 1.1655x; 1.1655x over previous
//
#include <hip/hip_runtime.h>
#include <stdint.h>

typedef __attribute__((ext_vector_type(8))) short s16x8;
typedef __attribute__((ext_vector_type(4))) float f32x4;

__device__ __forceinline__ short f2bf(float f){
  union { float f; uint32_t u; } v; v.f = f;
  uint32_t u = v.u;
  u += 0x7fffu + ((u >> 16) & 1u);
  return (short)(u >> 16);
}

#define MFMA16(a, b, c) __builtin_amdgcn_mfma_f32_16x16x32_bf16((a), (b), (c), 0, 0, 0)

// Fused TemporalEncoder. Round-16: barrier-free GRU (r14-validated dataflow)
// with BOTH spill mitigations -- the unexplored quadrant:
//  * Wih B-frags in LDS (r14): static regs ~190 (r15's Wih-in-regs = 238, spilled)
//  * sched_barrier(0) caging per G window (r15): only one 9-MFMA window's
//    temps live at a time (r14 uncaged -> 4 windows interleaved -> spilled)
// Whh (96 VGPR) + biases in regs. 14 barriers total; waves free-run.
__global__ __launch_bounds__(256, 2) void te_fused(
    const float* __restrict__ x,
    const float* __restrict__ w1, const float* __restrict__ b1,
    const float* __restrict__ w2, const float* __restrict__ b2,
    const float* __restrict__ Wih, const float* __restrict__ Whh,
    const float* __restrict__ bih, const float* __restrict__ bhh,
    float* __restrict__ out)
{
  __shared__ float x_s[16 * 100];      // 6400 B
  __shared__ short c1b[16 * 328];      // 10496 B
  __shared__ short s_b[16 * 640];      // 20480 B [t][seq][40-pad ch]
  __shared__ short wihL[12 * 64 * 8];  // 12288 B [tile][lane][8] scaled B-frags
  __shared__ float hscr[4][4 * 68];    // 4352 B  [wave][seq(4)][68-pad dim] f32

  const int tid  = threadIdx.x;
  const int lane = tid & 63;
  const int wv   = tid >> 6;
  const int l15  = lane & 15;
  const int lg   = lane >> 4;
  const int seq0 = blockIdx.x * 16;

  // ---- stage x ----
  {
    const float4* gx = reinterpret_cast<const float4*>(x + (size_t)seq0 * 100);
    float4* sx = reinterpret_cast<float4*>(x_s);
    for (int i = tid; i < 400; i += 256) sx[i] = gx[i];
  }
  // ---- Wih B-frags -> LDS (tiles 0-7: r/z rows x -log2e; 8-11: n x 2log2e) ----
  for (int i = tid; i < 12 * 64; i += 256) {
    const int tile = i >> 6, ln = i & 63;
    const int n  = tile * 16 + (ln & 15);
    const int k0 = (ln >> 4) * 8;
    const float gs = (tile < 8) ? -1.44269504f : 2.88539008f;
    short* dst = &wihL[i * 8];
#pragma unroll
    for (int j = 0; j < 8; ++j) dst[j] = f2bf(gs * Wih[n * 32 + k0 + j]);
  }

  // ---- Whh B-frags: 12 tiles in regs (rows n = 16g+l15, k = ks*32+lg*8+j) ----
  s16x8 WhhB[12][2];
#pragma unroll
  for (int g = 0; g < 12; ++g) {
    const float gs = (g < 8) ? -1.44269504f : 2.88539008f;
    const int n = 16 * g + l15;
#pragma unroll
    for (int ks = 0; ks < 2; ++ks) {
      const float* p = Whh + n * 64 + ks * 32 + lg * 8;
#pragma unroll
      for (int j = 0; j < 8; ++j) WhhB[g][ks][j] = f2bf(gs * p[j]);
    }
  }

  // ---- per-lane biases for (dim = 16G + l15) ----
  float brL[4], bzL[4], bxnL[4], bhnL[4];
#pragma unroll
  for (int G = 0; G < 4; ++G) {
    const int d = 16 * G + l15;
    brL[G]  = -1.44269504f * (bih[d] + bhh[d]);
    bzL[G]  = -1.44269504f * (bih[64 + d] + bhh[64 + d]);
    bxnL[G] =  2.88539008f * bih[128 + d];
    bhnL[G] =  2.88539008f * bhh[128 + d];
  }

  // ---- conv2 B-frags (r11/r14 verbatim) ----
  s16x8 cW2[2];
  f32x4 b2v4;
  {
    const int ch = 16 * (wv & 1) + l15;
    float bv = b2[ch];
    b2v4 = (f32x4){bv, bv, bv, bv};
#pragma unroll
    for (int ks = 0; ks < 2; ++ks) {
      s16x8 h8;
#pragma unroll
      for (int j = 0; j < 8; ++j) {
        const int k = ks * 32 + lg * 8 + j;
        const int g = k >> 4, ii = k & 15;
        h8[j] = (g < 3) ? f2bf(w2[ch * 48 + ii * 3 + g]) : (short)0;
      }
      cW2[ks] = h8;
    }
  }

  // ---- conv1 (r11/r14 verbatim) ----
  const int sl  = tid >> 4;
  const int chc = tid & 15;
  const float w1v0 = w1[chc * 3 + 0], w1v1 = w1[chc * 3 + 1], w1v2 = w1[chc * 3 + 2];
  const float b1v = b1[chc];

  // ---- pointers ----
  const short* c1Rd = &c1b[0] + l15 * 328 + lg * 8;
  short*       sWr  = &s_b[0] + (lg * 4) * 40 + (wv & 1) * 16 + l15;
  short*       c1Wr = &c1b[0] + sl * 328 + chc;
  const float* xRd  = &x_s[sl * 100];
  const int    ub   = (wv >> 1) * 8;
  const short* sRdW = &s_b[0] + (wv * 4 + (l15 & 3)) * 40 + lg * 8;
  float*       hscrW = &hscr[wv][0];
  const bool lb0 = (lg & 1) != 0;
  const bool lb1 = (lg & 2) != 0;

  __syncthreads();

  float hG[4] = {0.f, 0.f, 0.f, 0.f};
  s16x8 ah0 = (s16x8){0, 0, 0, 0, 0, 0, 0, 0};
  s16x8 ah1 = (s16x8){0, 0, 0, 0, 0, 0, 0, 0};

#define CONV1_PHASE(T0_, CLAMP_) do {                                         \
    float xa, xb;                                                             \
    if (CLAMP_) {                                                             \
      const int xi0 = (T0_) - 4, xi1 = (T0_) - 3;                             \
      xa = (xi0 < 0) ? 0.f : xRd[xi0 < 0 ? 0 : (xi0 > 99 ? 99 : xi0)];        \
      xb = (xi1 < 0) ? 0.f : xRd[xi1 < 0 ? 0 : (xi1 > 99 ? 99 : xi1)];        \
    } else {                                                                  \
      xa = xRd[(T0_) - 4]; xb = xRd[(T0_) - 3];                               \
    }                                                                         \
    _Pragma("unroll")                                                         \
    for (int i = 0; i < 19; ++i) {                                            \
      const int xi = (T0_) - 2 + i;                                           \
      float xc;                                                               \
      if (CLAMP_) {                                                           \
        const int idx = xi < 0 ? 0 : (xi > 99 ? 99 : xi);                     \
        xc = (xi < 0) ? 0.f : xRd[idx];                                       \
      } else {                                                                \
        xc = xRd[xi];                                                         \
      }                                                                       \
      float c = __builtin_fmaf(w1v0, xa,                                      \
                __builtin_fmaf(w1v1, xb,                                      \
                __builtin_fmaf(w1v2, xc, b1v)));                              \
      c = c > 0.f ? c : 0.f;                                                  \
      if (CLAMP_) c = (xi < 0) ? 0.f : c;                                     \
      uint32_t cu;                                                            \
      asm("v_cvt_pk_bf16_f32 %0, %1, %2" : "=v"(cu) : "v"(c), "v"(c));        \
      c1Wr[i * 16] = (short)(cu & 0xffff);                                    \
      xa = xb; xb = xc;                                                       \
    }                                                                         \
  } while (0)

#define CONV2_PHASE() do {                                                    \
    _Pragma("unroll")                                                         \
    for (int i = 0; i < 8; ++i) {                                             \
      const int u = ub + i;                                                   \
      s16x8 a0 = *reinterpret_cast<const s16x8*>(c1Rd + u * 16);              \
      s16x8 a1 = *reinterpret_cast<const s16x8*>(c1Rd + u * 16 + 32);         \
      f32x4 sa = MFMA16(a1, cW2[1], MFMA16(a0, cW2[0], b2v4));                \
      float m0 = sa[0] > 0.f ? sa[0] : 0.f;                                   \
      float m1 = sa[1] > 0.f ? sa[1] : 0.f;                                   \
      float m2 = sa[2] > 0.f ? sa[2] : 0.f;                                   \
      float m3 = sa[3] > 0.f ? sa[3] : 0.f;                                   \
      uint32_t u01, u23;                                                      \
      asm("v_cvt_pk_bf16_f32 %0, %1, %2" : "=v"(u01) : "v"(m0), "v"(m1));     \
      asm("v_cvt_pk_bf16_f32 %0, %1, %2" : "=v"(u23) : "v"(m2), "v"(m3));     \
      sWr[u * 640 +   0] = (short)(u01 & 0xffff);                             \
      sWr[u * 640 +  40] = (short)(u01 >> 16);                                \
      sWr[u * 640 +  80] = (short)(u23 & 0xffff);                             \
      sWr[u * 640 + 120] = (short)(u23 >> 16);                                \
    }                                                                         \
  } while (0)

  // select component lg of an f32x4 (D row = lg*4+reg -> seq = reg&3; reg = lg
  // yields this lane's element (seq = lg, dim = 16G+l15))
#define SEL4(Q_) (lb1 ? (lb0 ? (Q_)[3] : (Q_)[2]) : (lb0 ? (Q_)[1] : (Q_)[0]))

#pragma unroll 1
  for (int k = 0; k < 7; ++k) {
    const int t0 = k * 16;
    const int NS = (k < 6) ? 16 : 4;

    if (k == 0 || k == 6) CONV1_PHASE(t0, true);
    else                  CONV1_PHASE(t0, false);
    __syncthreads();
    CONV2_PHASE();
    __syncthreads();

#pragma unroll 1
    for (int tl = 0; tl < NS; ++tl) {
      s16x8 sfrag = *reinterpret_cast<const s16x8*>(sRdW + tl * 640);
      const f32x4 z4 = {0.f, 0.f, 0.f, 0.f};
#pragma unroll
      for (int G = 0; G < 4; ++G) {
        s16x8 wr = *reinterpret_cast<const s16x8*>(&wihL[((G    ) * 64 + lane) * 8]);
        s16x8 wz = *reinterpret_cast<const s16x8*>(&wihL[((G + 4) * 64 + lane) * 8]);
        s16x8 wn = *reinterpret_cast<const s16x8*>(&wihL[((G + 8) * 64 + lane) * 8]);
        __builtin_amdgcn_s_setprio(1);
        f32x4 Qr = MFMA16(ah1, WhhB[G][1],
                   MFMA16(ah0, WhhB[G][0],
                   MFMA16(sfrag, wr, z4)));
        f32x4 Qz = MFMA16(ah1, WhhB[G + 4][1],
                   MFMA16(ah0, WhhB[G + 4][0],
                   MFMA16(sfrag, wz, z4)));
        f32x4 Qxn = MFMA16(sfrag, wn, z4);
        f32x4 Qhn = MFMA16(ah1, WhhB[G + 8][1],
                    MFMA16(ah0, WhhB[G + 8][0], z4));
        __builtin_amdgcn_s_setprio(0);
        float pr = SEL4(Qr)  + brL[G];
        float pz = SEL4(Qz)  + bzL[G];
        float xn = SEL4(Qxn) + bxnL[G];
        float hn = SEL4(Qhn) + bhnL[G];
        float r = __builtin_amdgcn_rcpf(1.f + __builtin_amdgcn_exp2f(pr));
        float z = __builtin_amdgcn_rcpf(1.f + __builtin_amdgcn_exp2f(pz));
        float arg = __builtin_fmaf(r, hn, xn);
        float tn = __builtin_fmaf(-2.f,
                   __builtin_amdgcn_rcpf(__builtin_amdgcn_exp2f(arg) + 1.f), 1.f);
        float h = __builtin_fmaf(z, hG[G] - tn, tn);
        hG[G] = h;
        hscrW[lg * 68 + 16 * G + l15] = h;   // [seq=lg][dim]
        __builtin_amdgcn_sched_barrier(0);   // cage liveness to one G window
      }
      // rebuild next step's A-frags: row l15 -> seq l15&3, k = lg*8+j (+32)
      const float* hrow = hscrW + (l15 & 3) * 68 + lg * 8;
      f32x4 ha = *reinterpret_cast<const f32x4*>(hrow);
      f32x4 hb = *reinterpret_cast<const f32x4*>(hrow + 4);
      f32x4 hc = *reinterpret_cast<const f32x4*>(hrow + 32);
      f32x4 hd = *reinterpret_cast<const f32x4*>(hrow + 36);
      union { s16x8 v; uint32_t u[4]; } fa, fb;
      asm("v_cvt_pk_bf16_f32 %0, %1, %2" : "=v"(fa.u[0]) : "v"(ha[0]), "v"(ha[1]));
      asm("v_cvt_pk_bf16_f32 %0, %1, %2" : "=v"(fa.u[1]) : "v"(ha[2]), "v"(ha[3]));
      asm("v_cvt_pk_bf16_f32 %0, %1, %2" : "=v"(fa.u[2]) : "v"(hb[0]), "v"(hb[1]));
      asm("v_cvt_pk_bf16_f32 %0, %1, %2" : "=v"(fa.u[3]) : "v"(hb[2]), "v"(hb[3]));
      asm("v_cvt_pk_bf16_f32 %0, %1, %2" : "=v"(fb.u[0]) : "v"(hc[0]), "v"(hc[1]));
      asm("v_cvt_pk_bf16_f32 %0, %1, %2" : "=v"(fb.u[1]) : "v"(hc[2]), "v"(hc[3]));
      asm("v_cvt_pk_bf16_f32 %0, %1, %2" : "=v"(fb.u[2]) : "v"(hd[0]), "v"(hd[1]));
      asm("v_cvt_pk_bf16_f32 %0, %1, %2" : "=v"(fb.u[3]) : "v"(hd[2]), "v"(hd[3]));
      ah0 = fa.v; ah1 = fb.v;
    }
  }

  // ---- output: lane holds h(seq = wv*4+lg, dim = 16G+l15) ----
  {
    float* op = out + (size_t)(seq0 + wv * 4 + lg) * 64 + l15;
#pragma unroll
    for (int G = 0; G < 4; ++G) op[16 * G] = hG[G];
  }
}

extern "C" void kernel_launch(void* const* d_in, const int* in_sizes, int n_in,
                              void* d_out, int out_size, void* d_ws, size_t ws_size,
                              hipStream_t stream)
{
  (void)in_sizes; (void)n_in; (void)d_ws; (void)ws_size; (void)out_size;
  const float* x   = (const float*)d_in[0];
  const float* w1  = (const float*)d_in[1];
  const float* b1  = (const float*)d_in[2];
  const float* w2  = (const float*)d_in[3];
  const float* b2  = (const float*)d_in[4];
  const float* Wih = (const float*)d_in[5];
  const float* Whh = (const float*)d_in[6];
  const float* bih = (const float*)d_in[7];
  const float* bhh = (const float*)d_in[8];
  float* out = (float*)d_out;
  te_fused<<<512, 256, 0, stream>>>(x, w1, b1, w2, b2, Wih, Whh, bih, bhh, out);
}

// Round 17
// 67.743 us; speedup vs baseline: 2.4060x; 2.0643x over previous
//
#include <hip/hip_runtime.h>
#include <stdint.h>

typedef __attribute__((ext_vector_type(8))) short s16x8;
typedef __attribute__((ext_vector_type(4))) float f32x4;

__device__ __forceinline__ short f2bf(float f){
  union { float f; uint32_t u; } v; v.f = f;
  uint32_t u = v.u;
  u += 0x7fffu + ((u >> 16) & 1u);
  return (short)(u >> 16);
}

#define MFMA16(a, b, c) __builtin_amdgcn_mfma_f32_16x16x32_bf16((a), (b), (c), 0, 0, 0)

// Fused TemporalEncoder. Round-17 = round-11 RESTORED VERBATIM (session best:
// 67.7us, validated, no spill). Barrier-free branch (r12/r14/r15/r16) is
// exhausted: needs ~190 arch VGPRs, allocator caps at 128 under (256,2) ->
// scratch-spill-bound (140-163us). Lockstep M=16/grid=512/2-blocks-per-CU with
// chunk-batched convs + folded activation scales + re-associated gate chains
// is the best validated structure.
__global__ __launch_bounds__(256, 2) void te_fused(
    const float* __restrict__ x,
    const float* __restrict__ w1, const float* __restrict__ b1,
    const float* __restrict__ w2, const float* __restrict__ b2,
    const float* __restrict__ Wih, const float* __restrict__ Whh,
    const float* __restrict__ bih, const float* __restrict__ bhh,
    float* __restrict__ out)
{
  __shared__ float x_s[16 * 100];     // staged input rows (6400 B)
  __shared__ short hA[2][16 * 72];    // [buf][seq][72-pad dim] bf16 h (4608 B)
  __shared__ short c1b[16 * 328];     // [seq][19 tau][16 ch], 328-pad (10496 B)
  __shared__ short s_b[16 * 640];     // [16 t][16 seq][40-pad ch(32)] (20480 B)

  const int tid  = threadIdx.x;
  const int lane = tid & 63;
  const int wv   = tid >> 6;
  const int l15  = lane & 15;
  const int lg   = lane >> 4;
  const int seq0 = blockIdx.x * 16;

  if ((blockIdx.x >> 8) & 1) __builtin_amdgcn_s_sleep(7);

  // ---- stage x ----
  {
    const float4* gx = reinterpret_cast<const float4*>(x + (size_t)seq0 * 100);
    float4* sx = reinterpret_cast<float4*>(x_s);
    for (int i = tid; i < 400; i += 256) sx[i] = gx[i];
  }
  // zero h buf0
  {
    int* p = reinterpret_cast<int*>(&hA[0][0]);
    for (int i = tid; i < 576; i += 256) p[i] = 0;
  }

  // ---- weight B-fragments, activation scale folded in ----
  // g=0 (r), g=1 (z): rows x -log2e -> gate = rcp(1+exp2(pre))
  // g=2 (n): rows x 2log2e -> tanh = fma(-2, rcp(exp2(arg)+1), 1)
  s16x8 WhhHi[3][2], WihHi[3];
  f32x4 bias_r, bias_z, bias_xn, bias_hn;
#pragma unroll
  for (int g = 0; g < 3; ++g) {
    const float gs = (g < 2) ? -1.44269504f : 2.88539008f;
    const int n = 64 * g + 16 * wv + l15;
#pragma unroll
    for (int ks = 0; ks < 2; ++ks) {
      const float* p = Whh + n * 64 + ks * 32 + lg * 8;
#pragma unroll
      for (int j = 0; j < 8; ++j) WhhHi[g][ks][j] = f2bf(gs * p[j]);
    }
    const float* q = Wih + n * 32 + lg * 8;
#pragma unroll
    for (int j = 0; j < 8; ++j) WihHi[g][j] = f2bf(gs * q[j]);
    float bi = bih[n], bh = bhh[n];
    if (g == 0) { float v = gs * (bi + bh); bias_r = (f32x4){v, v, v, v}; }
    if (g == 1) { float v = gs * (bi + bh); bias_z = (f32x4){v, v, v, v}; }
    if (g == 2) { float vx = gs * bi, vh = gs * bh;
                  bias_xn = (f32x4){vx, vx, vx, vx};
                  bias_hn = (f32x4){vh, vh, vh, vh}; }
  }

  // conv2 B-frags: flat k = ks*32+lg*8+j, group g=k>>4: g<3 -> tap g, g==3 -> 0.
  s16x8 cW2[2];
  f32x4 b2v4;
  {
    const int ch = 16 * (wv & 1) + l15;
    float bv = b2[ch];
    b2v4 = (f32x4){bv, bv, bv, bv};
#pragma unroll
    for (int ks = 0; ks < 2; ++ks) {
      s16x8 h8;
#pragma unroll
      for (int j = 0; j < 8; ++j) {
        const int k = ks * 32 + lg * 8 + j;
        const int g = k >> 4, ii = k & 15;
        h8[j] = (g < 3) ? f2bf(w2[ch * 48 + ii * 3 + g]) : (short)0;
      }
      cW2[ks] = h8;
    }
  }

  // conv1
  const int sl  = tid >> 4;
  const int chc = tid & 15;
  const float w1v0 = w1[chc * 3 + 0], w1v1 = w1[chc * 3 + 1], w1v2 = w1[chc * 3 + 2];
  const float b1v = b1[chc];

  // ---- hoisted LDS pointers ----
  const short* sRd  = &s_b[0]   + l15 * 40 + lg * 8;
  const short* hRd  = &hA[0][0] + l15 * 72 + lg * 8;
  short*       hWr  = &hA[0][0] + (lg * 4) * 72 + 16 * wv + l15;
  const short* c1Rd = &c1b[0]   + l15 * 328 + lg * 8;
  short*       sWr  = &s_b[0]   + (lg * 4) * 40 + (wv & 1) * 16 + l15;
  short*       c1Wr = &c1b[0]   + sl * 328 + chc;
  const float* xRd  = &x_s[sl * 100];
  const int    ub   = (wv >> 1) * 8;

  __syncthreads();

  float hreg[4] = {0.f, 0.f, 0.f, 0.f};
  s16x8 asv;                      // prefetched s A-frag for the current step

#define CONV1_PHASE(T0_, CLAMP_) do {                                         \
    float xa, xb;                                                             \
    if (CLAMP_) {                                                             \
      const int xi0 = (T0_) - 4, xi1 = (T0_) - 3;                             \
      xa = (xi0 < 0) ? 0.f : xRd[xi0 < 0 ? 0 : (xi0 > 99 ? 99 : xi0)];        \
      xb = (xi1 < 0) ? 0.f : xRd[xi1 < 0 ? 0 : (xi1 > 99 ? 99 : xi1)];        \
    } else {                                                                  \
      xa = xRd[(T0_) - 4]; xb = xRd[(T0_) - 3];                               \
    }                                                                         \
    _Pragma("unroll")                                                         \
    for (int i = 0; i < 19; ++i) {                                            \
      const int xi = (T0_) - 2 + i;                                           \
      float xc;                                                               \
      if (CLAMP_) {                                                           \
        const int idx = xi < 0 ? 0 : (xi > 99 ? 99 : xi);                     \
        xc = (xi < 0) ? 0.f : xRd[idx];                                       \
      } else {                                                                \
        xc = xRd[xi];                                                         \
      }                                                                       \
      float c = __builtin_fmaf(w1v0, xa,                                      \
                __builtin_fmaf(w1v1, xb,                                      \
                __builtin_fmaf(w1v2, xc, b1v)));                              \
      c = c > 0.f ? c : 0.f;                                                  \
      if (CLAMP_) c = (xi < 0) ? 0.f : c;                                     \
      uint32_t cu;                                                            \
      asm("v_cvt_pk_bf16_f32 %0, %1, %2" : "=v"(cu) : "v"(c), "v"(c));        \
      c1Wr[i * 16] = (short)(cu & 0xffff);                                    \
      xa = xb; xb = xc;                                                       \
    }                                                                         \
  } while (0)

#define CONV2_PHASE() do {                                                    \
    _Pragma("unroll")                                                         \
    for (int i = 0; i < 8; ++i) {                                             \
      const int u = ub + i;                                                   \
      s16x8 a0 = *reinterpret_cast<const s16x8*>(c1Rd + u * 16);              \
      s16x8 a1 = *reinterpret_cast<const s16x8*>(c1Rd + u * 16 + 32);         \
      f32x4 sa = MFMA16(a1, cW2[1], MFMA16(a0, cW2[0], b2v4));                \
      float m0 = sa[0] > 0.f ? sa[0] : 0.f;                                   \
      float m1 = sa[1] > 0.f ? sa[1] : 0.f;                                   \
      float m2 = sa[2] > 0.f ? sa[2] : 0.f;                                   \
      float m3 = sa[3] > 0.f ? sa[3] : 0.f;                                   \
      uint32_t u01, u23;                                                      \
      asm("v_cvt_pk_bf16_f32 %0, %1, %2" : "=v"(u01) : "v"(m0), "v"(m1));     \
      asm("v_cvt_pk_bf16_f32 %0, %1, %2" : "=v"(u23) : "v"(m2), "v"(m3));     \
      sWr[u * 640 +   0] = (short)(u01 & 0xffff);                             \
      sWr[u * 640 +  40] = (short)(u01 >> 16);                                \
      sWr[u * 640 +  80] = (short)(u23 & 0xffff);                             \
      sWr[u * 640 + 120] = (short)(u23 >> 16);                                \
    }                                                                         \
  } while (0)

#define GSTEP(TL) do {                                                        \
    const int rb_ = (TL) & 1, wb_ = rb_ ^ 1;                                  \
    s16x8 ah0 = *reinterpret_cast<const s16x8*>(hRd + rb_ * 1152);            \
    s16x8 ah1 = *reinterpret_cast<const s16x8*>(hRd + rb_ * 1152 + 32);       \
    __builtin_amdgcn_s_setprio(1);                                            \
    f32x4 sr = MFMA16(asv, WihHi[0], bias_r);    /* s-only, issues early */   \
    f32x4 sz = MFMA16(asv, WihHi[1], bias_z);                                 \
    f32x4 xn = MFMA16(asv, WihHi[2], bias_xn);                                \
    f32x4 pr = MFMA16(ah1, WhhHi[0][1],          /* 2-deep after h-read */    \
               MFMA16(ah0, WhhHi[0][0], sr));                                 \
    f32x4 pz = MFMA16(ah1, WhhHi[1][1],                                       \
               MFMA16(ah0, WhhHi[1][0], sz));                                 \
    f32x4 hn = MFMA16(ah1, WhhHi[2][1],                                       \
               MFMA16(ah0, WhhHi[2][0], bias_hn));                            \
    __builtin_amdgcn_s_setprio(0);                                            \
    asv = *reinterpret_cast<const s16x8*>(sRd + (((TL) + 1) & 15) * 640);     \
    float hnew[4];                                                            \
    _Pragma("unroll")                                                         \
    for (int i2 = 0; i2 < 4; ++i2) {                                          \
      float r = __builtin_amdgcn_rcpf(1.f + __builtin_amdgcn_exp2f(pr[i2]));  \
      float z = __builtin_amdgcn_rcpf(1.f + __builtin_amdgcn_exp2f(pz[i2]));  \
      float arg = __builtin_fmaf(r, hn[i2], xn[i2]);                          \
      float et = __builtin_amdgcn_exp2f(arg);                                 \
      float tn = __builtin_fmaf(-2.f, __builtin_amdgcn_rcpf(et + 1.f), 1.f);  \
      float h = __builtin_fmaf(z, hreg[i2] - tn, tn);                         \
      hreg[i2] = h; hnew[i2] = h;                                             \
    }                                                                         \
    uint32_t p01, p23;                                                        \
    asm("v_cvt_pk_bf16_f32 %0, %1, %2" : "=v"(p01) : "v"(hnew[0]), "v"(hnew[1])); \
    asm("v_cvt_pk_bf16_f32 %0, %1, %2" : "=v"(p23) : "v"(hnew[2]), "v"(hnew[3])); \
    hWr[wb_ * 1152 +   0] = (short)(p01 & 0xffff);                            \
    hWr[wb_ * 1152 +  72] = (short)(p01 >> 16);                               \
    hWr[wb_ * 1152 + 144] = (short)(p23 & 0xffff);                            \
    hWr[wb_ * 1152 + 216] = (short)(p23 >> 16);                               \
    __syncthreads();                                                          \
  } while (0)

#define G16 do { asv = *reinterpret_cast<const s16x8*>(sRd);                  \
                 GSTEP(0);  GSTEP(1);  GSTEP(2);  GSTEP(3);                   \
                 GSTEP(4);  GSTEP(5);  GSTEP(6);  GSTEP(7);                   \
                 GSTEP(8);  GSTEP(9);  GSTEP(10); GSTEP(11);                  \
                 GSTEP(12); GSTEP(13); GSTEP(14); GSTEP(15); } while (0)

  // ---- chunk 0 (edge-clamped conv1) ----
  CONV1_PHASE(0, true);
  __syncthreads();
  CONV2_PHASE();
  __syncthreads();
  G16;

  // ---- chunks 1..5 (no clamps) ----
#pragma unroll 1
  for (int k = 1; k < 6; ++k) {
    const int t0 = k * 16;
    CONV1_PHASE(t0, false);
    __syncthreads();
    CONV2_PHASE();
    __syncthreads();
    G16;
  }

  // ---- chunk 6 (edge-clamped, 4 steps) ----
  CONV1_PHASE(96, true);
  __syncthreads();
  CONV2_PHASE();
  __syncthreads();
  asv = *reinterpret_cast<const s16x8*>(sRd);
  GSTEP(0); GSTEP(1); GSTEP(2); GSTEP(3);

#pragma unroll
  for (int i2 = 0; i2 < 4; ++i2) {
    out[(size_t)(seq0 + lg * 4 + i2) * 64 + 16 * wv + l15] = hreg[i2];
  }
}

extern "C" void kernel_launch(void* const* d_in, const int* in_sizes, int n_in,
                              void* d_out, int out_size, void* d_ws, size_t ws_size,
                              hipStream_t stream)
{
  (void)in_sizes; (void)n_in; (void)d_ws; (void)ws_size; (void)out_size;
  const float* x   = (const float*)d_in[0];
  const float* w1  = (const float*)d_in[1];
  const float* b1  = (const float*)d_in[2];
  const float* w2  = (const float*)d_in[3];
  const float* b2  = (const float*)d_in[4];
  const float* Wih = (const float*)d_in[5];
  const float* Whh = (const float*)d_in[6];
  const float* bih = (const float*)d_in[7];
  const float* bhh = (const float*)d_in[8];
  float* out = (float*)d_out;
  te_fused<<<512, 256, 0, stream>>>(x, w1, b1, w2, b2, Wih, Whh, bih, bhh, out);
}